// Round 14
// baseline (92.559 us; speedup 1.0000x reference)
//
#include <hip/hip_runtime.h>
#include <hip/hip_bf16.h>
#include <math.h>

#define NPC   2048          // points per cloud
#define NC    8             // clouds
#define NTOT  (NPC * NC)    // 16384
#define KMAX  32
#define R2    0.04f         // f32(0.04) — boundary-exact vs numpy's f64 compare

typedef short bf16x8  __attribute__((ext_vector_type(8)));
typedef float f32x16  __attribute__((ext_vector_type(16)));

// f32 -> bf16 round-to-nearest-even (finite values only)
__device__ __forceinline__ unsigned int f2bf(float f) {
    unsigned int u = __float_as_uint(f);
    return (u + 0x7FFFu + ((u >> 16) & 1u)) >> 16;
}

// packed f32x2 -> bf16x2 (RNE), src0 in LOW half (validated round 5)
__device__ __forceinline__ unsigned int pkbf(float a, float b) {
    unsigned int r;
    asm("v_cvt_pk_bf16_f32 %0, %1, %2" : "=v"(r) : "v"(a), "v"(b));
    return r;
}

// count of set bits in m at positions < lane (wave64) — 2 VALU instrs
__device__ __forceinline__ int mbcnt64(unsigned long long m) {
    return (int)__builtin_amdgcn_mbcnt_hi((unsigned int)(m >> 32),
            __builtin_amdgcn_mbcnt_lo((unsigned int)m, 0u));
}

// ---- k-permuted epilogue (validated round 8): relu+pack 8 consecutive acc regs -> operand frag ----
// Weight k-rows pre-permuted by P(kk,hi,j) = (j&3)+4*hi+8*(2*(kk&1)+(j>>2))+32*(kk>>1).
__device__ __forceinline__ bf16x8 mk_frag(const f32x16& a, int off) {  // off: 0 or 8 (compile-time)
    int4 w;
    w.x = (int)pkbf(fmaxf(a[off+0],0.f), fmaxf(a[off+1],0.f));
    w.y = (int)pkbf(fmaxf(a[off+2],0.f), fmaxf(a[off+3],0.f));
    w.z = (int)pkbf(fmaxf(a[off+4],0.f), fmaxf(a[off+5],0.f));
    w.w = (int)pkbf(fmaxf(a[off+6],0.f), fmaxf(a[off+7],0.f));
    return __builtin_bit_cast(bf16x8, w);
}

// ============ kernel 1 (tiny): weight frags (k-permuted, validated r8/r9) + tail copies ============
__global__ __launch_bounds__(512) void prep_small(
    const float* __restrict__ pos, const int* __restrict__ batch,
    const float* __restrict__ W1, const float* __restrict__ b1,
    const float* __restrict__ W2, const float* __restrict__ b2,
    const float* __restrict__ W3,
    unsigned short* __restrict__ wf, float* __restrict__ out)
{
    int b = blockIdx.x, tid = threadIdx.x;
    if (b < 28) {
        int g = b * 512 + tid;                // 0..14335
        if (g < 1024) {
            // layer1 A = W1^T padded K=16, bias at k=6 (natural k order)
            int j = g & 7, lane = (g >> 3) & 63, t = g >> 9;
            int k = (lane >> 5)*8 + j, ch = t*32 + (lane & 31);
            float v = (k < 6) ? W1[k*64 + ch] : (k == 6 ? b1[ch] : 0.f);
            wf[g] = (unsigned short)f2bf(v);
        } else if (g < 6144) {
            // GEMM2 A = W2^T (K=80, bias row at logical k=64); k-rows permuted by P
            int g2 = g - 1024;
            int j = g2 & 7, lane = (g2 >> 3) & 63, f = g2 >> 9;
            int t = f / 5, kk = f % 5;
            int hi = lane >> 5, row = t*32 + (lane & 31);
            float v;
            if (kk < 4) {
                int k = (j & 3) + 4*hi + 8*(2*(kk & 1) + (j >> 2)) + 32*(kk >> 1);
                v = W2[k*64 + row];
            } else {
                v = (hi == 0 && j == 0) ? b2[row] : 0.f;   // bias row, matches `onef` B-frag
            }
            wf[g] = (unsigned short)f2bf(v);
        } else {
            // GEMM3 B = W3 (K=64); k-rows permuted by P
            int g3 = g - 6144;
            int j = g3 & 7, lane = (g3 >> 3) & 63, f = g3 >> 9;
            int n = f >> 2, kk = f & 3;
            int hi = lane >> 5, col = n*32 + (lane & 31);
            int k = (j & 3) + 4*hi + 8*(2*(kk & 1) + (j >> 2)) + 32*(kk >> 1);
            wf[g] = (unsigned short)f2bf(W3[k*128 + col]);
        }
    } else {
        // tail copies: 128 blocks x 512 = 65536 = NTOT*3 (pos) + NTOT (batch)
        int i = (b - 28) * 512 + tid;
        if (i < NTOT*3) out[NTOT*128 + i] = pos[i];
        else            out[NTOT*131 + (i - NTOT*3)] = (float)batch[i - NTOT*3];
    }
}

// ============ kernel 2: FUSED search + MLP, 16 waves x 2 queries = 32 queries/block ============
// Pair-packed pos layout; search tests 2 points x 2 queries per lane-iteration, point reads
// shared across both queries. MLP (r13-validated body) runs per query sequentially.
// LDS: sPxy4 16K + sPz2 8K + sW 26K + snbr 4K = 55.3 KB -> 2 blocks/CU = 32 waves/CU.
__global__ __launch_bounds__(1024, 8) void fused_kernel(
    const float* __restrict__ x, const float* __restrict__ pos,
    const unsigned short* __restrict__ wf, const float* __restrict__ b3,
    float* __restrict__ out)
{
    __shared__ float4 sPxy4[NPC/2];   // 16384 B: {x(2k),y(2k),x(2k+1),y(2k+1)}
    __shared__ float2 sPz2[NPC/2];    //  8192 B: {z(2k), z(2k+1)}
    __shared__ int4   sW[1664];       // 26624 B: wg2a(640) | wg3b(1024)
    __shared__ int    snbr[16*64];    //  4096 B: per wave: [0..31] q0 slots, [32..63] q1 slots

    const int tid  = threadIdx.x;
    const int lane = tid & 63, wave = tid >> 6;
    const int e = lane & 31, hi = lane >> 5;
    const int q0    = __builtin_amdgcn_readfirstlane(blockIdx.x * 32 + wave * 2);
    const int base  = (q0 >> 11) << 11;           // cloud start row (q0,q1 same cloud)
    const int q0l   = q0 - base;                  // even local index

    // ---- Phase A: parallel staging — half block: pos pairs; other half: weight frags ----
    if (tid < 512) {
        const float4* src = (const float4*)(pos + 3*base);   // 1536 float4 = 2048 points
        float4 f0 = src[3*tid], f1 = src[3*tid+1], f2 = src[3*tid+2];
        sPxy4[2*tid+0] = make_float4(f0.x, f0.y, f0.w, f1.x);
        sPz2 [2*tid+0] = make_float2(f0.z, f1.y);
        sPxy4[2*tid+1] = make_float4(f1.z, f1.w, f2.y, f2.z);
        sPz2 [2*tid+1] = make_float2(f2.x, f2.w);
    } else {
        const int4* wsrc = (const int4*)(wf + 1024);
        int t = tid - 512;
        #pragma unroll
        for (int it = 0; it < 4; ++it) {
            int idx = it*512 + t;
            if (idx < 1664) sW[idx] = wsrc[idx];
        }
    }
    // layer1 W frags straight to registers (global, L2-resident)
    bf16x8 wA1_0 = *(const bf16x8*)(wf + (0*64 + lane)*8);
    bf16x8 wA1_1 = *(const bf16x8*)(wf + (1*64 + lane)*8);
    float b3v[4];
    #pragma unroll
    for (int n = 0; n < 4; ++n) b3v[n] = b3[n*32 + e];
    __syncthreads();   // the ONLY block-wide barrier

    // both query centers from ONE pair slot (q0l even)
    const float4 qv = sPxy4[q0l >> 1];
    const float2 qzv = sPz2[q0l >> 1];
    const float q0x = qv.x, q0y = qv.y, q0z = qzv.x;
    const float q1x = qv.z, q1y = qv.w, q1z = qzv.y;

    // ---- Phase B: radius search, 2 points x 2 queries per lane-iteration (exact arith) ----
    int cnt0 = 0, cnt1 = 0;
    for (int j0 = 0; j0 < NPC && (cnt0 < KMAX || cnt1 < KMAX); j0 += 128) {
        float4 pp = sPxy4[(j0 >> 1) + lane];   // points A=j0+2*lane, B=A+1
        float2 zz = sPz2[(j0 >> 1) + lane];
        if (cnt0 < KMAX) {
            float dax = __fsub_rn(pp.x, q0x), day = __fsub_rn(pp.y, q0y), daz = __fsub_rn(zz.x, q0z);
            float dbx = __fsub_rn(pp.z, q0x), dby = __fsub_rn(pp.w, q0y), dbz = __fsub_rn(zz.y, q0z);
            float d2a = __fadd_rn(__fadd_rn(__fmul_rn(dax,dax), __fmul_rn(day,day)), __fmul_rn(daz,daz));
            float d2b = __fadd_rn(__fadd_rn(__fmul_rn(dbx,dbx), __fmul_rn(dby,dby)), __fmul_rn(dbz,dbz));
            bool va = d2a <= R2, vb = d2b <= R2;
            unsigned long long me = __ballot(va), mo = __ballot(vb);
            int se = cnt0 + mbcnt64(me) + mbcnt64(mo);
            int so = se + (va ? 1 : 0);
            if (va && se < KMAX) snbr[(wave << 6) + se] = j0 + 2*lane;
            if (vb && so < KMAX) snbr[(wave << 6) + so] = j0 + 2*lane + 1;
            cnt0 += (int)__popcll(me) + (int)__popcll(mo);
        }
        if (cnt1 < KMAX) {
            float dax = __fsub_rn(pp.x, q1x), day = __fsub_rn(pp.y, q1y), daz = __fsub_rn(zz.x, q1z);
            float dbx = __fsub_rn(pp.z, q1x), dby = __fsub_rn(pp.w, q1y), dbz = __fsub_rn(zz.y, q1z);
            float d2a = __fadd_rn(__fadd_rn(__fmul_rn(dax,dax), __fmul_rn(day,day)), __fmul_rn(daz,daz));
            float d2b = __fadd_rn(__fadd_rn(__fmul_rn(dbx,dbx), __fmul_rn(dby,dby)), __fmul_rn(dbz,dbz));
            bool va = d2a <= R2, vb = d2b <= R2;
            unsigned long long me = __ballot(va), mo = __ballot(vb);
            int se = cnt1 + mbcnt64(me) + mbcnt64(mo);
            int so = se + (va ? 1 : 0);
            if (va && se < KMAX) snbr[(wave << 6) + 32 + se] = j0 + 2*lane;
            if (vb && so < KMAX) snbr[(wave << 6) + 32 + so] = j0 + 2*lane + 1;
            cnt1 += (int)__popcll(me) + (int)__popcll(mo);
        }
    }
    if (cnt0 > KMAX) cnt0 = KMAX;
    if (cnt1 > KMAX) cnt1 = KMAX;

    const unsigned int one_w = pkbf(1.0f, 0.0f);
    int4 ow = {0,0,0,0};
    if (!hi) ow.x = (int)one_w;
    const bf16x8 onef = __builtin_bit_cast(bf16x8, ow);   // GEMM2 bias-row B-frag

    // ---- Phase C: MLP per query (r13-validated body; snbr wave-private) ----
    auto MLP = [&](int q, int ql, int cnt, int nbase, float qx, float qy, float qz) {
        int jl = (e < cnt) ? snbr[nbase + e] : ql;
        float4 pv = sPxy4[jl >> 1];
        float2 zv = sPz2[jl >> 1];
        bool odd = (jl & 1) != 0;
        float pjx = odd ? pv.z : pv.x;
        float pjy = odd ? pv.w : pv.y;
        float pjz = odd ? zv.y : zv.x;
        int gj = base + jl;
        float xj0 = x[3*gj], xj1 = x[3*gj+1], xj2 = x[3*gj+2];

        float r0 = pjx - qx, r1 = pjy - qy, r2 = pjz - qz;
        int4 mw;
        mw.x = hi ? 0 : (int)pkbf(xj0, xj1);
        mw.y = hi ? 0 : (int)pkbf(xj2, r0);
        mw.z = hi ? 0 : (int)pkbf(r1, r2);
        mw.w = hi ? 0 : (int)one_w;
        bf16x8 msgf = __builtin_bit_cast(bf16x8, mw);

        // layer1 (swapped): C1^T[64 ch][32 e], K=16
        __builtin_amdgcn_s_setprio(1);
        f32x16 acc0 = {}, acc1 = {};
        acc0 = __builtin_amdgcn_mfma_f32_32x32x16_bf16(wA1_0, msgf, acc0, 0, 0, 0);
        acc1 = __builtin_amdgcn_mfma_f32_32x32x16_bf16(wA1_1, msgf, acc1, 0, 0, 0);
        __builtin_amdgcn_s_setprio(0);
        bf16x8 h1f[4];
        h1f[0] = mk_frag(acc0, 0);
        h1f[1] = mk_frag(acc0, 8);
        h1f[2] = mk_frag(acc1, 0);
        h1f[3] = mk_frag(acc1, 8);

        // GEMM2 (swapped): C2^T[64][32], K=80 (bias row via onef)
        __builtin_amdgcn_s_setprio(1);
        f32x16 c20 = {}, c21 = {};
        #pragma unroll
        for (int kk = 0; kk < 4; ++kk) {
            c20 = __builtin_amdgcn_mfma_f32_32x32x16_bf16(
                    *(const bf16x8*)&sW[(0*5 + kk)*64 + lane], h1f[kk], c20, 0, 0, 0);
            c21 = __builtin_amdgcn_mfma_f32_32x32x16_bf16(
                    *(const bf16x8*)&sW[(1*5 + kk)*64 + lane], h1f[kk], c21, 0, 0, 0);
        }
        c20 = __builtin_amdgcn_mfma_f32_32x32x16_bf16(
                *(const bf16x8*)&sW[(0*5 + 4)*64 + lane], onef, c20, 0, 0, 0);
        c21 = __builtin_amdgcn_mfma_f32_32x32x16_bf16(
                *(const bf16x8*)&sW[(1*5 + 4)*64 + lane], onef, c21, 0, 0, 0);
        __builtin_amdgcn_s_setprio(0);
        bf16x8 h2f[4];
        h2f[0] = mk_frag(c20, 0);
        h2f[1] = mk_frag(c20, 8);
        h2f[2] = mk_frag(c21, 0);
        h2f[3] = mk_frag(c21, 8);

        // GEMM3 (non-swapped): C[32 e][128 out], bias folded into C-init; fused max
        const bool full = (cnt == 32);
        #pragma unroll
        for (int n = 0; n < 4; ++n) {
            f32x16 c;
            #pragma unroll
            for (int r = 0; r < 16; ++r) c[r] = b3v[n];
            __builtin_amdgcn_s_setprio(1);
            #pragma unroll
            for (int kk = 0; kk < 4; ++kk)
                c = __builtin_amdgcn_mfma_f32_32x32x16_bf16(
                        h2f[kk], *(const bf16x8*)&sW[640 + (n*4 + kk)*64 + lane], c, 0, 0, 0);
            __builtin_amdgcn_s_setprio(0);
            float m;
            if (full) {
                float t0 = fmaxf(fmaxf(c[0],  c[1]),  c[2]);
                float t1 = fmaxf(fmaxf(c[3],  c[4]),  c[5]);
                float t2 = fmaxf(fmaxf(c[6],  c[7]),  c[8]);
                float t3 = fmaxf(fmaxf(c[9],  c[10]), c[11]);
                float t4 = fmaxf(fmaxf(c[12], c[13]), c[14]);
                m = fmaxf(fmaxf(t0, t1), c[15]);
                m = fmaxf(fmaxf(m, t2), t3);
                m = fmaxf(m, t4);
            } else {
                m = -INFINITY;
                #pragma unroll
                for (int reg = 0; reg < 16; ++reg) {
                    int r = (reg & 3) + 8*(reg >> 2) + 4*hi;   // edge slot
                    m = fmaxf(m, (r < cnt) ? c[reg] : -INFINITY);
                }
            }
            m = fmaxf(m, __shfl_xor(m, 32));
            if (hi == 0) out[q*128 + n*32 + e] = m;
        }
    };

    MLP(q0,     q0l,     cnt0, (wave << 6),      q0x, q0y, q0z);
    MLP(q0 + 1, q0l + 1, cnt1, (wave << 6) + 32, q1x, q1y, q1z);
}

extern "C" void kernel_launch(void* const* d_in, const int* in_sizes, int n_in,
                              void* d_out, int out_size, void* d_ws, size_t ws_size,
                              hipStream_t stream) {
    const float* x     = (const float*)d_in[0];
    const float* pos   = (const float*)d_in[1];
    const int*   batch = (const int*)d_in[2];
    const float* W1    = (const float*)d_in[3];
    const float* b1    = (const float*)d_in[4];
    const float* W2    = (const float*)d_in[5];
    const float* b2    = (const float*)d_in[6];
    const float* W3    = (const float*)d_in[7];
    const float* b3    = (const float*)d_in[8];
    float* out = (float*)d_out;

    unsigned short* wfrag = (unsigned short*)d_ws;   // 14336 bf16 (28 KB)

    prep_small<<<156, 512, 0, stream>>>(pos, batch, W1, b1, W2, b2, W3, wfrag, out);
    fused_kernel<<<NTOT / 32, 1024, 0, stream>>>(x, pos, wfrag, b3, out);
}

// Round 15
// 36.424 us; speedup vs baseline: 2.5412x; 2.5412x over previous
//
#include <hip/hip_runtime.h>
#include <hip/hip_bf16.h>
#include <math.h>

#define NPC   2048          // points per cloud
#define NC    8             // clouds
#define NTOT  (NPC * NC)    // 16384
#define KMAX  32
#define R2    0.04f         // f32(0.04) — boundary-exact vs numpy's f64 compare

typedef short bf16x8  __attribute__((ext_vector_type(8)));
typedef float f32x16  __attribute__((ext_vector_type(16)));

// f32 -> bf16 round-to-nearest-even (finite values only)
__device__ __forceinline__ unsigned int f2bf(float f) {
    unsigned int u = __float_as_uint(f);
    return (u + 0x7FFFu + ((u >> 16) & 1u)) >> 16;
}

// packed f32x2 -> bf16x2 (RNE), src0 in LOW half (validated round 5)
__device__ __forceinline__ unsigned int pkbf(float a, float b) {
    unsigned int r;
    asm("v_cvt_pk_bf16_f32 %0, %1, %2" : "=v"(r) : "v"(a), "v"(b));
    return r;
}

// count of set bits in m at positions < lane (wave64) — 2 VALU instrs
__device__ __forceinline__ int mbcnt64(unsigned long long m) {
    return (int)__builtin_amdgcn_mbcnt_hi((unsigned int)(m >> 32),
            __builtin_amdgcn_mbcnt_lo((unsigned int)m, 0u));
}

// ---- k-permuted epilogue (validated round 8): relu+pack 8 consecutive acc regs -> operand frag ----
// Weight k-rows pre-permuted by P(kk,hi,j) = (j&3)+4*hi+8*(2*(kk&1)+(j>>2))+32*(kk>>1).
__device__ __forceinline__ bf16x8 mk_frag(const f32x16& a, int off) {  // off: 0 or 8 (compile-time)
    int4 w;
    w.x = (int)pkbf(fmaxf(a[off+0],0.f), fmaxf(a[off+1],0.f));
    w.y = (int)pkbf(fmaxf(a[off+2],0.f), fmaxf(a[off+3],0.f));
    w.z = (int)pkbf(fmaxf(a[off+4],0.f), fmaxf(a[off+5],0.f));
    w.w = (int)pkbf(fmaxf(a[off+6],0.f), fmaxf(a[off+7],0.f));
    return __builtin_bit_cast(bf16x8, w);
}

// ============ kernel 1 (tiny): weight frags (k-permuted, validated r8/r9) + tail copies ============
__global__ __launch_bounds__(512) void prep_small(
    const float* __restrict__ pos, const int* __restrict__ batch,
    const float* __restrict__ W1, const float* __restrict__ b1,
    const float* __restrict__ W2, const float* __restrict__ b2,
    const float* __restrict__ W3,
    unsigned short* __restrict__ wf, float* __restrict__ out)
{
    int b = blockIdx.x, tid = threadIdx.x;
    if (b < 28) {
        int g = b * 512 + tid;                // 0..14335
        if (g < 1024) {
            // layer1 A = W1^T padded K=16, bias at k=6 (natural k order)
            int j = g & 7, lane = (g >> 3) & 63, t = g >> 9;
            int k = (lane >> 5)*8 + j, ch = t*32 + (lane & 31);
            float v = (k < 6) ? W1[k*64 + ch] : (k == 6 ? b1[ch] : 0.f);
            wf[g] = (unsigned short)f2bf(v);
        } else if (g < 6144) {
            // GEMM2 A = W2^T (K=80, bias row at logical k=64); k-rows permuted by P
            int g2 = g - 1024;
            int j = g2 & 7, lane = (g2 >> 3) & 63, f = g2 >> 9;
            int t = f / 5, kk = f % 5;
            int hi = lane >> 5, row = t*32 + (lane & 31);
            float v;
            if (kk < 4) {
                int k = (j & 3) + 4*hi + 8*(2*(kk & 1) + (j >> 2)) + 32*(kk >> 1);
                v = W2[k*64 + row];
            } else {
                v = (hi == 0 && j == 0) ? b2[row] : 0.f;   // bias row, matches `onef` B-frag
            }
            wf[g] = (unsigned short)f2bf(v);
        } else {
            // GEMM3 B = W3 (K=64); k-rows permuted by P
            int g3 = g - 6144;
            int j = g3 & 7, lane = (g3 >> 3) & 63, f = g3 >> 9;
            int n = f >> 2, kk = f & 3;
            int hi = lane >> 5, col = n*32 + (lane & 31);
            int k = (j & 3) + 4*hi + 8*(2*(kk & 1) + (j >> 2)) + 32*(kk >> 1);
            wf[g] = (unsigned short)f2bf(W3[k*128 + col]);
        }
    } else {
        // tail copies: 128 blocks x 512 = 65536 = NTOT*3 (pos) + NTOT (batch)
        int i = (b - 28) * 512 + tid;
        if (i < NTOT*3) out[NTOT*128 + i] = pos[i];
        else            out[NTOT*131 + (i - NTOT*3)] = (float)batch[i - NTOT*3];
    }
}

// ============ kernel 2: FUSED search + MLP, 16 waves = 16 queries/block (r13 structure) ============
// Pair-packed pos: one ds_read_b128 + ds_read_b64 tests 2 points/lane (128 pts/iter).
// LDS: sPxy4 16K + sPz2 8K + sW 26K + snbr 2K = 53.2 KB -> 2 blocks/CU = 32 waves/CU (HW max).
__global__ __launch_bounds__(1024, 8) void fused_kernel(
    const float* __restrict__ x, const float* __restrict__ pos,
    const unsigned short* __restrict__ wf, const float* __restrict__ b3,
    float* __restrict__ out)
{
    __shared__ float4 sPxy4[NPC/2];   // 16384 B: {x(2k),y(2k),x(2k+1),y(2k+1)}
    __shared__ float2 sPz2[NPC/2];    //  8192 B: {z(2k), z(2k+1)}
    __shared__ int4   sW[1664];       // 26624 B: wg2a(640) | wg3b(1024)
    __shared__ int    snbr[16*32];    //  2048 B: wave-private neighbor slots

    const int tid  = threadIdx.x;
    const int lane = tid & 63, wave = tid >> 6;
    const int e = lane & 31, hi = lane >> 5;
    const int q     = blockIdx.x * 16 + wave;     // this wave's query (global row)
    const int base  = (q >> 11) << 11;            // cloud start row
    const int ql    = q - base;                   // local query index

    // ---- Phase A: parallel staging — half block: pos pairs; other half: weight frags ----
    if (tid < 512) {
        const float4* src = (const float4*)(pos + 3*base);   // 1536 float4 = 2048 points
        float4 f0 = src[3*tid], f1 = src[3*tid+1], f2 = src[3*tid+2];
        sPxy4[2*tid+0] = make_float4(f0.x, f0.y, f0.w, f1.x);
        sPz2 [2*tid+0] = make_float2(f0.z, f1.y);
        sPxy4[2*tid+1] = make_float4(f1.z, f1.w, f2.y, f2.z);
        sPz2 [2*tid+1] = make_float2(f2.x, f2.w);
    } else {
        const int4* wsrc = (const int4*)(wf + 1024);
        int t = tid - 512;
        #pragma unroll
        for (int it = 0; it < 4; ++it) {
            int idx = it*512 + t;
            if (idx < 1664) sW[idx] = wsrc[idx];
        }
    }
    // layer1 W frags straight to registers (global, L2-resident)
    bf16x8 wA1_0 = *(const bf16x8*)(wf + (0*64 + lane)*8);
    bf16x8 wA1_1 = *(const bf16x8*)(wf + (1*64 + lane)*8);
    float b3v[4];
    #pragma unroll
    for (int n = 0; n < 4; ++n) b3v[n] = b3[n*32 + e];
    __syncthreads();   // the ONLY block-wide barrier

    // query center (pair slot, pick by parity)
    const float4 qv  = sPxy4[ql >> 1];
    const float2 qzv = sPz2[ql >> 1];
    const bool qodd  = (ql & 1) != 0;
    const float qx = qodd ? qv.z : qv.x;
    const float qy = qodd ? qv.w : qv.y;
    const float qz = qodd ? qzv.y : qzv.x;

    // ---- Phase B: radius search, 2 points/lane-iteration (exact arith; r14-validated prefix) ----
    int cnt = 0;
    for (int j0 = 0; j0 < NPC && cnt < KMAX; j0 += 128) {
        float4 pp = sPxy4[(j0 >> 1) + lane];   // points A=j0+2*lane, B=A+1
        float2 zz = sPz2[(j0 >> 1) + lane];
        float dax = __fsub_rn(pp.x, qx), day = __fsub_rn(pp.y, qy), daz = __fsub_rn(zz.x, qz);
        float dbx = __fsub_rn(pp.z, qx), dby = __fsub_rn(pp.w, qy), dbz = __fsub_rn(zz.y, qz);
        float d2a = __fadd_rn(__fadd_rn(__fmul_rn(dax,dax), __fmul_rn(day,day)), __fmul_rn(daz,daz));
        float d2b = __fadd_rn(__fadd_rn(__fmul_rn(dbx,dbx), __fmul_rn(dby,dby)), __fmul_rn(dbz,dbz));
        bool va = d2a <= R2, vb = d2b <= R2;
        unsigned long long me = __ballot(va), mo = __ballot(vb);
        int se = cnt + mbcnt64(me) + mbcnt64(mo);   // evens<me + odds<mo before this even point
        int so = se + (va ? 1 : 0);                 // odd point follows its even partner
        if (va && se < KMAX) snbr[(wave << 5) + se] = j0 + 2*lane;
        if (vb && so < KMAX) snbr[(wave << 5) + so] = j0 + 2*lane + 1;
        cnt += (int)__popcll(me) + (int)__popcll(mo);
    }
    if (cnt > KMAX) cnt = KMAX;     // wave-uniform

    // ---- Phase C: MLP (r13-validated body; snbr wave-private, lgkmcnt orders it) ----
    int jl = (e < cnt) ? snbr[(wave << 5) + e] : ql;
    float4 pv = sPxy4[jl >> 1];
    float2 zv = sPz2[jl >> 1];
    bool odd = (jl & 1) != 0;
    float pjx = odd ? pv.z : pv.x;
    float pjy = odd ? pv.w : pv.y;
    float pjz = odd ? zv.y : zv.x;
    int gj = base + jl;
    float xj0 = x[3*gj], xj1 = x[3*gj+1], xj2 = x[3*gj+2];

    const unsigned int one_w = pkbf(1.0f, 0.0f);
    int4 ow = {0,0,0,0};
    if (!hi) ow.x = (int)one_w;
    const bf16x8 onef = __builtin_bit_cast(bf16x8, ow);   // GEMM2 bias-row B-frag

    float r0 = pjx - qx, r1 = pjy - qy, r2 = pjz - qz;
    int4 mw;
    mw.x = hi ? 0 : (int)pkbf(xj0, xj1);
    mw.y = hi ? 0 : (int)pkbf(xj2, r0);
    mw.z = hi ? 0 : (int)pkbf(r1, r2);
    mw.w = hi ? 0 : (int)one_w;
    bf16x8 msgf = __builtin_bit_cast(bf16x8, mw);

    // layer1 (swapped): C1^T[64 ch][32 e], K=16
    __builtin_amdgcn_s_setprio(1);
    f32x16 acc0 = {}, acc1 = {};
    acc0 = __builtin_amdgcn_mfma_f32_32x32x16_bf16(wA1_0, msgf, acc0, 0, 0, 0);
    acc1 = __builtin_amdgcn_mfma_f32_32x32x16_bf16(wA1_1, msgf, acc1, 0, 0, 0);
    __builtin_amdgcn_s_setprio(0);
    bf16x8 h1f[4];
    h1f[0] = mk_frag(acc0, 0);
    h1f[1] = mk_frag(acc0, 8);
    h1f[2] = mk_frag(acc1, 0);
    h1f[3] = mk_frag(acc1, 8);

    // GEMM2 (swapped): C2^T[64][32], K=80 (bias row via onef)
    __builtin_amdgcn_s_setprio(1);
    f32x16 c20 = {}, c21 = {};
    #pragma unroll
    for (int kk = 0; kk < 4; ++kk) {
        c20 = __builtin_amdgcn_mfma_f32_32x32x16_bf16(
                *(const bf16x8*)&sW[(0*5 + kk)*64 + lane], h1f[kk], c20, 0, 0, 0);
        c21 = __builtin_amdgcn_mfma_f32_32x32x16_bf16(
                *(const bf16x8*)&sW[(1*5 + kk)*64 + lane], h1f[kk], c21, 0, 0, 0);
    }
    c20 = __builtin_amdgcn_mfma_f32_32x32x16_bf16(
            *(const bf16x8*)&sW[(0*5 + 4)*64 + lane], onef, c20, 0, 0, 0);
    c21 = __builtin_amdgcn_mfma_f32_32x32x16_bf16(
            *(const bf16x8*)&sW[(1*5 + 4)*64 + lane], onef, c21, 0, 0, 0);
    __builtin_amdgcn_s_setprio(0);
    bf16x8 h2f[4];
    h2f[0] = mk_frag(c20, 0);
    h2f[1] = mk_frag(c20, 8);
    h2f[2] = mk_frag(c21, 0);
    h2f[3] = mk_frag(c21, 8);

    // GEMM3 (non-swapped): C[32 e][128 out], bias folded into C-init; fused max over edges
    const bool full = (cnt == 32);
    #pragma unroll
    for (int n = 0; n < 4; ++n) {
        f32x16 c;
        #pragma unroll
        for (int r = 0; r < 16; ++r) c[r] = b3v[n];
        __builtin_amdgcn_s_setprio(1);
        #pragma unroll
        for (int kk = 0; kk < 4; ++kk)
            c = __builtin_amdgcn_mfma_f32_32x32x16_bf16(
                    h2f[kk], *(const bf16x8*)&sW[640 + (n*4 + kk)*64 + lane], c, 0, 0, 0);
        __builtin_amdgcn_s_setprio(0);
        float m;
        if (full) {
            // 3-ary nesting -> v_max3_f32 (T17)
            float t0 = fmaxf(fmaxf(c[0],  c[1]),  c[2]);
            float t1 = fmaxf(fmaxf(c[3],  c[4]),  c[5]);
            float t2 = fmaxf(fmaxf(c[6],  c[7]),  c[8]);
            float t3 = fmaxf(fmaxf(c[9],  c[10]), c[11]);
            float t4 = fmaxf(fmaxf(c[12], c[13]), c[14]);
            m = fmaxf(fmaxf(t0, t1), c[15]);
            m = fmaxf(fmaxf(m, t2), t3);
            m = fmaxf(m, t4);
        } else {
            m = -INFINITY;
            #pragma unroll
            for (int reg = 0; reg < 16; ++reg) {
                int r = (reg & 3) + 8*(reg >> 2) + 4*hi;   // edge slot
                m = fmaxf(m, (r < cnt) ? c[reg] : -INFINITY);
            }
        }
        m = fmaxf(m, __shfl_xor(m, 32));
        if (hi == 0) out[q*128 + n*32 + e] = m;
    }
}

extern "C" void kernel_launch(void* const* d_in, const int* in_sizes, int n_in,
                              void* d_out, int out_size, void* d_ws, size_t ws_size,
                              hipStream_t stream) {
    const float* x     = (const float*)d_in[0];
    const float* pos   = (const float*)d_in[1];
    const int*   batch = (const int*)d_in[2];
    const float* W1    = (const float*)d_in[3];
    const float* b1    = (const float*)d_in[4];
    const float* W2    = (const float*)d_in[5];
    const float* b2    = (const float*)d_in[6];
    const float* W3    = (const float*)d_in[7];
    const float* b3    = (const float*)d_in[8];
    float* out = (float*)d_out;

    unsigned short* wfrag = (unsigned short*)d_ws;   // 14336 bf16 (28 KB)

    prep_small<<<156, 512, 0, stream>>>(pos, batch, W1, b1, W2, b2, W3, wfrag, out);
    fused_kernel<<<NTOT / 16, 1024, 0, stream>>>(x, pos, wfrag, b3, out);
}